// Round 2
// baseline (1748.214 us; speedup 1.0000x reference)
//
#include <hip/hip_runtime.h>
#include <math.h>

#define NSTEPS 500
#define BATCH  1024
#define DX     32
#define DW     32
#define HDIM   128
#define BETA   0.5f
#define EPSG   1e-4f

__device__ __forceinline__ float tanh_fast(float x) {
    // tanh(x) = (e^{2x}-1)/(e^{2x}+1); clamp so e^{2x} cannot overflow.
    float xc = fminf(fmaxf(x, -15.f), 15.f);
    float e  = __expf(2.f * xc);
    return (e - 1.f) / (e + 1.f);
}

// 128 threads = 2 waves per block, one batch row per block, grid = 1024.
// Each thread owns FULL weight columns in registers:
//   w1[33]  : column j of W1  (layers use j = tid, 128 columns)
//   w2[128] : column j of W2
//   w3[32]  : quarter-K slice (kq = tid>>5) of column d3 = tid&31 of W3
// => each layer is one barrier (activation broadcast read -> reg dot -> tanh -> write).
__global__ __launch_bounds__(128, 2)
void sde_kernel(const float* __restrict__ x0, const float* __restrict__ ts,
                const float* __restrict__ dWs,
                const float* __restrict__ W1, const float* __restrict__ b1,
                const float* __restrict__ W2, const float* __restrict__ b2,
                const float* __restrict__ W3, const float* __restrict__ b3,
                const float* __restrict__ G,  const float* __restrict__ mu,
                const float* __restrict__ vt, float* __restrict__ out)
{
    __shared__ __align__(16) float sx  [DX];
    __shared__ __align__(16) float sh1 [HDIM];
    __shared__ __align__(16) float sh2 [HDIM];
    __shared__ __align__(16) float spart3[4][DX];
    __shared__ __align__(16) float sprra [4][DX];
    __shared__ __align__(16) float sr  [DX];
    __shared__ __align__(16) float sdW [DX];
    __shared__ __align__(16) float su  [DX];
    __shared__ __align__(16) float sGt [DX][DX];   // sGt[k][d] = G[d][k]
    __shared__ __align__(16) float sa  [DX][DX];   // a = G G^T, [k][d]
    __shared__ __align__(16) float smu [DX];
    __shared__ __align__(16) float svt [DX];

    const int tid = threadIdx.x;
    const int row = blockIdx.x;
    const int j   = tid;        // column for layers 1 & 2
    const int d3  = tid & 31;   // output dim for layer 3
    const int kq  = tid >> 5;   // K-quarter for layer 3: 0..3

    // ---- weights into registers (coalesced across lanes: consecutive j) ----
    float w1r[33];
    #pragma unroll
    for (int k = 0; k < 33; ++k) w1r[k] = W1[k * HDIM + j];
    float w2r[128];
    #pragma unroll
    for (int k = 0; k < 128; ++k) w2r[k] = W2[k * HDIM + j];
    float w3r[32];
    #pragma unroll
    for (int k = 0; k < 32; ++k) w3r[k] = W3[(kq * 32 + k) * DW + d3];
    const float b1r = b1[j];
    const float b2r = b2[j];
    const float b3r = b3[d3];

    // ---- shared init ----
    if (tid < DX) sx[tid] = x0[(size_t)row * DX + tid];
    for (int idx = tid; idx < DX * DX; idx += 128) {
        int i = idx >> 5, k = idx & 31;
        sGt[k][i] = G[i * DW + k];       // transpose into LDS
    }
    if (tid < DX) { smu[tid] = mu[tid]; svt[tid] = vt[tid]; }
    __syncthreads();
    for (int idx = tid; idx < DX * DX; idx += 128) {
        int i = idx >> 5, jj = idx & 31;
        float acc = 0.f;
        #pragma unroll
        for (int k = 0; k < DW; ++k) acc += sGt[k][i] * sGt[k][jj];
        sa[i][jj] = acc;                 // a[i][jj] = sum_k G[i][k] G[jj][k]
    }
    __syncthreads();

    const float T = ts[NSTEPS];
    float tcur = ts[0];
    float llr = 0.f;

    float* xs_out = out;
    float* vs_out = out + (size_t)NSTEPS * BATCH * DX;
    float* ll_out = out + (size_t)2 * NSTEPS * BATCH * DX;

    #pragma unroll 1
    for (int s = 0; s < NSTEPS; ++s) {
        const float tn     = ts[s + 1];
        const float dt     = tn - tcur;
        const float sqdt   = sqrtf(dt);
        const float invrem = 1.0f / (T - tcur + EPSG);

        // ---- P0 (folded into L1 phase): r and scaled dW ----
        if (tid < DX) {
            sr[tid] = (svt[tid] - sx[tid]) * invrem;
        } else if (tid < 2 * DX) {
            int d = tid - DX;
            sdW[d] = dWs[(size_t)s * (BATCH * DW) + (size_t)row * DW + d] * sqdt;
        }

        // ---- L1: full-K dot (K=33) + tanh, one write ----
        {
            float a0 = tcur * w1r[0], a1 = 0.f, a2 = 0.f, a3 = 0.f;
            const float4* xv4 = (const float4*)sx;
            #pragma unroll
            for (int q = 0; q < 8; ++q) {
                float4 xv = xv4[q];
                a0 += xv.x * w1r[4 * q + 1];
                a1 += xv.y * w1r[4 * q + 2];
                a2 += xv.z * w1r[4 * q + 3];
                a3 += xv.w * w1r[4 * q + 4];
            }
            sh1[j] = tanh_fast(((a0 + a1) + (a2 + a3)) + b1r);
        }
        __syncthreads();   // 1

        // ---- L2: full-K dot (K=128) + tanh, one write ----
        {
            float a0 = 0.f, a1 = 0.f, a2 = 0.f, a3 = 0.f;
            const float4* h4 = (const float4*)sh1;
            #pragma unroll
            for (int q = 0; q < 32; ++q) {
                float4 h = h4[q];
                a0 += h.x * w2r[4 * q + 0];
                a1 += h.y * w2r[4 * q + 1];
                a2 += h.z * w2r[4 * q + 2];
                a3 += h.w * w2r[4 * q + 3];
            }
            sh2[j] = tanh_fast(((a0 + a1) + (a2 + a3)) + b2r);
        }
        __syncthreads();   // 2

        // ---- L3 quarter-K partials + r@a quarter partials ----
        {
            const float4* h4 = (const float4*)(sh2 + kq * 32);
            float c0 = 0.f, c1 = 0.f;
            #pragma unroll
            for (int q = 0; q < 8; ++q) {
                float4 h = h4[q];
                c0 += h.x * w3r[4 * q + 0] + h.y * w3r[4 * q + 1];
                c1 += h.z * w3r[4 * q + 2] + h.w * w3r[4 * q + 3];
            }
            spart3[kq][d3] = c0 + c1;

            const float4* r4 = (const float4*)(sr + kq * 8);
            float acc = 0.f;
            #pragma unroll
            for (int q = 0; q < 2; ++q) {
                float4 r = r4[q];
                int kb = kq * 8 + q * 4;
                acc += r.x * sa[kb][d3]     + r.y * sa[kb + 1][d3]
                     + r.z * sa[kb + 2][d3] + r.w * sa[kb + 3][d3];
            }
            sprra[kq][d3] = acc;
        }
        __syncthreads();   // 3

        // ---- combine + x-update, wave-synchronous in lanes 0..31 ----
        if (tid < DX) {
            const int d = tid;
            float v  = ((spart3[0][d] + spart3[1][d]) + (spart3[2][d] + spart3[3][d])) + b3r;
            float ra = ((sprra[0][d] + sprra[1][d]) + (sprra[2][d] + sprra[3][d]));
            float xv = sx[d];
            float rv = sr[d];
            float fb = BETA * (smu[d] - xv);
            float u  = v * dt + sdW[d];            // u = v*dt + dW*sqrt(dt)
            su[d] = u;
            size_t off = (size_t)s * (BATCH * DX) + (size_t)row * DX + d;
            vs_out[off] = v;

            float term = fb * rv - 0.5f * rv * ra;
            term += __shfl_down(term, 16);
            term += __shfl_down(term, 8);
            term += __shfl_down(term, 4);
            term += __shfl_down(term, 2);
            term += __shfl_down(term, 1);
            if (d == 0) llr += term * dt;

            // x update: needs all of su — same wave, DS ops in-order, no barrier
            float acc = 0.f, acc2 = 0.f;
            const float4* u4p = (const float4*)su;
            #pragma unroll
            for (int q = 0; q < 8; ++q) {
                float4 u4 = u4p[q];
                int kb = 4 * q;
                acc  += u4.x * sGt[kb][d]     + u4.y * sGt[kb + 1][d];
                acc2 += u4.z * sGt[kb + 2][d] + u4.w * sGt[kb + 3][d];
            }
            float xn = xv + (fb + ra) * dt + (acc + acc2);
            sx[d] = xn;
            xs_out[off] = xn;
        }
        tcur += dt;
        __syncthreads();   // 4 (end of step: protects sx, sr, sh1/sh2 reuse)
    }

    if (tid == 0) ll_out[row] = llr;
}

extern "C" void kernel_launch(void* const* d_in, const int* in_sizes, int n_in,
                              void* d_out, int out_size, void* d_ws, size_t ws_size,
                              hipStream_t stream) {
    const float* x0 = (const float*)d_in[0];
    const float* ts = (const float*)d_in[1];
    const float* dWs = (const float*)d_in[2];
    const float* W1 = (const float*)d_in[3];
    const float* b1 = (const float*)d_in[4];
    const float* W2 = (const float*)d_in[5];
    const float* b2 = (const float*)d_in[6];
    const float* W3 = (const float*)d_in[7];
    const float* b3 = (const float*)d_in[8];
    const float* G  = (const float*)d_in[9];
    const float* mu = (const float*)d_in[10];
    const float* vt = (const float*)d_in[11];
    hipLaunchKernelGGL(sde_kernel, dim3(BATCH), dim3(128), 0, stream,
                       x0, ts, dWs, W1, b1, W2, b2, W3, b3, G, mu, vt, (float*)d_out);
}

// Round 3
// 1158.592 us; speedup vs baseline: 1.5089x; 1.5089x over previous
//
#include <hip/hip_runtime.h>
#include <math.h>

#define NSTEPS 500
#define BATCH  1024
#define DX     32
#define DW     32
#define HDIM   128
#define BETA   0.5f
#define EPSG   1e-4f
#define MROWS  16
#define LDF    36    // padded f32 row stride for [16][32] LDS arrays
#define LDH    136   // padded ushort row stride for [16][128] bf16 LDS arrays
#define LDI    72    // padded ushort row stride for [16][64] bf16 inp

typedef short bf8_t __attribute__((ext_vector_type(8)));
typedef float f4_t  __attribute__((ext_vector_type(4)));

__device__ __forceinline__ f4_t MFMA(bf8_t a, bf8_t b, f4_t c) {
    return __builtin_amdgcn_mfma_f32_16x16x32_bf16(a, b, c, 0, 0, 0);
}

__device__ __forceinline__ unsigned short f2bf(float x) {   // RNE f32->bf16
    unsigned u = __float_as_uint(x);
    u += 0x7fffu + ((u >> 16) & 1u);
    return (unsigned short)(u >> 16);
}
__device__ __forceinline__ float bf2f(unsigned short h) {
    return __uint_as_float(((unsigned)h) << 16);
}

__device__ __forceinline__ float tanh_fast(float x) {
    float xc = fminf(fmaxf(x, -15.f), 15.f);
    float e  = __expf(2.f * xc);
    return (e - 1.f) / (e + 1.f);
}

// hi/lo bf16 split of 8 consecutive f32 in LDS (16B-aligned): ~17-bit mantissa pair
__device__ __forceinline__ void hilo8(const float* p, bf8_t& hi, bf8_t& lo) {
    f4_t A = *(const f4_t*)p;
    f4_t B = *(const f4_t*)(p + 4);
    #pragma unroll
    for (int j = 0; j < 4; ++j) {
        unsigned short h = f2bf(A[j]);
        hi[j] = (short)h; lo[j] = (short)f2bf(A[j] - bf2f(h));
    }
    #pragma unroll
    for (int j = 0; j < 4; ++j) {
        unsigned short h = f2bf(B[j]);
        hi[4 + j] = (short)h; lo[4 + j] = (short)f2bf(B[j] - bf2f(h));
    }
}

// 16 rows/block, 4 waves (256 thr), grid = 64.  MFMA 16x16x32 bf16 everywhere.
// Waves split the N dim: L1/L2 N=128 -> 32 cols/wave; L3(v)+uG^T on waves 0-1,
// r@a on waves 2-3, Gval on wave 2.  r@a and u@G^T use hi/lo split (3 MFMAs).
__global__ __launch_bounds__(256, 1)
void sde_kernel(const float* __restrict__ x0, const float* __restrict__ ts,
                const float* __restrict__ dWs,
                const float* __restrict__ W1, const float* __restrict__ b1,
                const float* __restrict__ W2, const float* __restrict__ b2,
                const float* __restrict__ W3, const float* __restrict__ b3,
                const float* __restrict__ G,  const float* __restrict__ mu,
                const float* __restrict__ vt, float* __restrict__ out)
{
    __shared__ __align__(16) unsigned short sinp[MROWS * LDI]; // bf16 [t|x|0..0]
    __shared__ __align__(16) unsigned short sh1 [MROWS * LDH]; // bf16 h1
    __shared__ __align__(16) unsigned short sh2 [MROWS * LDH]; // bf16 h2
    __shared__ __align__(16) float sxc [MROWS * LDF];          // f32 x
    __shared__ __align__(16) float sr  [MROWS * LDF];          // f32 r
    __shared__ __align__(16) float sra [MROWS * LDF];          // f32 r@a
    __shared__ __align__(16) float su  [MROWS * LDF];          // f32 u = v*dt + dW'
    __shared__ __align__(16) float sdwu[MROWS * LDF];          // f32 dW*sqrt(dt)
    __shared__ __align__(16) float sa  [DX * DX];              // f32 a = G G^T
    __shared__ __align__(16) float sts [NSTEPS + 1];
    __shared__ __align__(16) float smu [DX], svt[DX];

    const int tid  = threadIdx.x;
    const int wid  = tid >> 6;
    const int lane = tid & 63;
    const int m16  = lane & 15;   // MFMA A-row / C-col
    const int quad = lane >> 4;   // MFMA k-group / C-rowgroup
    const int r0   = blockIdx.x * MROWS;

    // ---------------- init ----------------
    for (int i = tid; i < MROWS * LDI; i += 256) sinp[i] = 0;
    for (int i = tid; i <= NSTEPS; i += 256) sts[i] = ts[i];
    if (tid < DX) { smu[tid] = mu[tid]; svt[tid] = vt[tid]; }
    __syncthreads();

    const int prow = tid >> 4;         // 0..15 (row for 2-elem-per-thread ops)
    const int pd2  = (tid & 15) * 2;   // 0,2,..,30
    {
        float xa = x0[(r0 + prow) * DX + pd2];
        float xb = x0[(r0 + prow) * DX + pd2 + 1];
        sxc[prow * LDF + pd2]     = xa;
        sxc[prow * LDF + pd2 + 1] = xb;
        sinp[prow * LDI + 1 + pd2]     = f2bf(xa);
        sinp[prow * LDI + 1 + pd2 + 1] = f2bf(xb);
        if (tid < MROWS) sinp[tid * LDI] = f2bf(sts[0]);
    }
    for (int idx = tid; idx < DX * DX; idx += 256) {
        int i = idx >> 5, jj = idx & 31;
        float acc = 0.f;
        for (int k = 0; k < DW; ++k) acc += G[i * DW + k] * G[jj * DW + k];
        sa[i * DX + jj] = acc;
    }
    __syncthreads();

    // ---------------- resident B-fragments (bf16, B[k][n]: n=lane&15, k=quad*8+j) ----
    bf8_t w1f[2][2], w2f[4][2];
    float b1c[2], b2c[2];
    #pragma unroll
    for (int nt = 0; nt < 2; ++nt) {
        int n = wid * 32 + nt * 16 + m16;
        #pragma unroll
        for (int kt = 0; kt < 2; ++kt)
            #pragma unroll
            for (int j = 0; j < 8; ++j) {
                int k = kt * 32 + quad * 8 + j;
                w1f[kt][nt][j] = (short)((k < DX + 1) ? f2bf(W1[k * HDIM + n]) : 0);
            }
        #pragma unroll
        for (int kt = 0; kt < 4; ++kt)
            #pragma unroll
            for (int j = 0; j < 8; ++j) {
                int k = kt * 32 + quad * 8 + j;
                w2f[kt][nt][j] = (short)f2bf(W2[k * HDIM + n]);
            }
        b1c[nt] = b1[n];
        b2c[nt] = b2[n];
    }
    bf8_t w3f[4], ghi, glo, ahi, alo;
    float b3c = 0.f;
    if (wid < 2) {
        int n = wid * 16 + m16;
        #pragma unroll
        for (int kt = 0; kt < 4; ++kt)
            #pragma unroll
            for (int j = 0; j < 8; ++j)
                w3f[kt][j] = (short)f2bf(W3[(kt * 32 + quad * 8 + j) * DW + n]);
        b3c = b3[n];
        #pragma unroll
        for (int j = 0; j < 8; ++j) {       // Gt[k][n] = G[n][k], hi/lo split
            float g = G[n * DW + quad * 8 + j];
            unsigned short h = f2bf(g);
            ghi[j] = (short)h; glo[j] = (short)f2bf(g - bf2f(h));
        }
        ahi = w3f[0]; alo = w3f[0];         // dead init (keeps allocation sane)
    } else {
        int n = (wid - 2) * 16 + m16;
        #pragma unroll
        for (int j = 0; j < 8; ++j) {       // a[k][n], hi/lo split
            float av = sa[(quad * 8 + j) * DX + n];
            unsigned short h = f2bf(av);
            ahi[j] = (short)h; alo[j] = (short)f2bf(av - bf2f(h));
        }
        #pragma unroll
        for (int kt = 0; kt < 4; ++kt) w3f[kt] = ahi;  // dead init
        ghi = ahi; glo = alo;                          // dead init
    }

    // dW prefetch for step 0
    float pw0 = dWs[(size_t)(r0 + prow) * DW + pd2];
    float pw1 = dWs[(size_t)(r0 + prow) * DW + pd2 + 1];

    const float T = sts[NSTEPS];
    float tcur = sts[0];
    float llr = 0.f;

    float* xs_out = out;
    float* vs_out = out + (size_t)NSTEPS * BATCH * DX;
    float* ll_out = out + (size_t)2 * NSTEPS * BATCH * DX;

    __syncthreads();

    #pragma unroll 1
    for (int s = 0; s < NSTEPS; ++s) {
        const float dt     = sts[s + 1] - sts[s];
        const float sqdt   = sqrtf(dt);
        const float invrem = 1.f / (T - tcur + EPSG);

        // ---- Phase A: L1 MFMA; also write r, dW'; prefetch next dW ----
        {
            const unsigned short* p = sinp + m16 * LDI + quad * 8;
            bf8_t a0 = *(const bf8_t*)p;
            bf8_t a1 = *(const bf8_t*)(p + 32);
            f4_t z1n0 = {0, 0, 0, 0}, z1n1 = {0, 0, 0, 0};
            z1n0 = MFMA(a0, w1f[0][0], z1n0);
            z1n1 = MFMA(a0, w1f[0][1], z1n1);
            z1n0 = MFMA(a1, w1f[1][0], z1n0);
            z1n1 = MFMA(a1, w1f[1][1], z1n1);

            float xa = sxc[prow * LDF + pd2], xb = sxc[prow * LDF + pd2 + 1];
            sr[prow * LDF + pd2]     = (svt[pd2]     - xa) * invrem;
            sr[prow * LDF + pd2 + 1] = (svt[pd2 + 1] - xb) * invrem;
            sdwu[prow * LDF + pd2]     = pw0 * sqdt;
            sdwu[prow * LDF + pd2 + 1] = pw1 * sqdt;
            int sn = (s + 1 < NSTEPS) ? s + 1 : s;
            pw0 = dWs[(size_t)sn * (BATCH * DW) + (size_t)(r0 + prow) * DW + pd2];
            pw1 = dWs[(size_t)sn * (BATCH * DW) + (size_t)(r0 + prow) * DW + pd2 + 1];

            #pragma unroll
            for (int i = 0; i < 4; ++i) {
                int row = quad * 4 + i;
                sh1[row * LDH + wid * 32 + m16]      = f2bf(tanh_fast(z1n0[i] + b1c[0]));
                sh1[row * LDH + wid * 32 + 16 + m16] = f2bf(tanh_fast(z1n1[i] + b1c[1]));
            }
        }
        __syncthreads();   // 1

        // ---- Phase B: L2 ----
        {
            f4_t z2n0 = {0, 0, 0, 0}, z2n1 = {0, 0, 0, 0};
            #pragma unroll
            for (int kt = 0; kt < 4; ++kt) {
                bf8_t af = *(const bf8_t*)(sh1 + m16 * LDH + kt * 32 + quad * 8);
                z2n0 = MFMA(af, w2f[kt][0], z2n0);
                z2n1 = MFMA(af, w2f[kt][1], z2n1);
            }
            #pragma unroll
            for (int i = 0; i < 4; ++i) {
                int row = quad * 4 + i;
                sh2[row * LDH + wid * 32 + m16]      = f2bf(tanh_fast(z2n0[i] + b2c[0]));
                sh2[row * LDH + wid * 32 + 16 + m16] = f2bf(tanh_fast(z2n1[i] + b2c[1]));
            }
        }
        __syncthreads();   // 2

        // ---- Phase C: waves 0-1: v = h2@W3;  waves 2-3: ra = r@a (hi/lo) ----
        f4_t vc = {0, 0, 0, 0};
        if (wid < 2) {
            #pragma unroll
            for (int kt = 0; kt < 4; ++kt) {
                bf8_t af = *(const bf8_t*)(sh2 + m16 * LDH + kt * 32 + quad * 8);
                vc = MFMA(af, w3f[kt], vc);
            }
        } else {
            bf8_t rhi, rlo;
            hilo8(sr + m16 * LDF + quad * 8, rhi, rlo);
            f4_t ra = {0, 0, 0, 0};
            ra = MFMA(rhi, ahi, ra);
            ra = MFMA(rhi, alo, ra);
            ra = MFMA(rlo, ahi, ra);
            int colb = (wid - 2) * 16 + m16;
            #pragma unroll
            for (int i = 0; i < 4; ++i) sra[(quad * 4 + i) * LDF + colb] = ra[i];
        }
        __syncthreads();   // 3

        // ---- Phase D: u + vs store (w0-1); Gval (w2); next-t write (w3) ----
        if (wid < 2) {
            int colb = wid * 16 + m16;
            #pragma unroll
            for (int i = 0; i < 4; ++i) {
                int row = quad * 4 + i;
                float v = vc[i] + b3c;
                float u = v * dt + sdwu[row * LDF + colb];
                su[row * LDF + colb] = u;
                vs_out[(size_t)s * (BATCH * DX) + (size_t)(r0 + row) * DX + colb] = v;
            }
        } else if (wid == 2) {
            int row = lane >> 2, q = lane & 3;
            const float* xr  = sxc + row * LDF + q * 8;
            const float* rr  = sr  + row * LDF + q * 8;
            const float* rar = sra + row * LDF + q * 8;
            float t8 = 0.f;
            #pragma unroll
            for (int d = 0; d < 8; ++d) {
                float fb = BETA * (smu[q * 8 + d] - xr[d]);
                t8 += fb * rr[d] - 0.5f * rr[d] * rar[d];
            }
            t8 += __shfl_down(t8, 2);
            t8 += __shfl_down(t8, 1);
            if (q == 0) llr += t8 * dt;
        } else {
            float tn = tcur + dt;
            if (lane < MROWS) sinp[lane * LDI] = f2bf(tn);
        }
        __syncthreads();   // 4

        // ---- Phase E: x update via u@G^T (hi/lo) on waves 0-1 ----
        if (wid < 2) {
            bf8_t uhi, ulo;
            hilo8(su + m16 * LDF + quad * 8, uhi, ulo);
            f4_t xg = {0, 0, 0, 0};
            xg = MFMA(uhi, ghi, xg);
            xg = MFMA(uhi, glo, xg);
            xg = MFMA(ulo, ghi, xg);
            int colb = wid * 16 + m16;
            float muc = smu[colb];
            #pragma unroll
            for (int i = 0; i < 4; ++i) {
                int row = quad * 4 + i;
                float xv = sxc[row * LDF + colb];
                float ra = sra[row * LDF + colb];
                float fb = BETA * (muc - xv);
                float xn = xv + (fb + ra) * dt + xg[i];
                sxc[row * LDF + colb] = xn;
                sinp[row * LDI + 1 + colb] = f2bf(xn);
                xs_out[(size_t)s * (BATCH * DX) + (size_t)(r0 + row) * DX + colb] = xn;
            }
        }
        tcur += dt;
        __syncthreads();   // 5
    }

    if (wid == 2 && (lane & 3) == 0) ll_out[r0 + (lane >> 2)] = llr;
}

extern "C" void kernel_launch(void* const* d_in, const int* in_sizes, int n_in,
                              void* d_out, int out_size, void* d_ws, size_t ws_size,
                              hipStream_t stream) {
    const float* x0 = (const float*)d_in[0];
    const float* ts = (const float*)d_in[1];
    const float* dWs = (const float*)d_in[2];
    const float* W1 = (const float*)d_in[3];
    const float* b1 = (const float*)d_in[4];
    const float* W2 = (const float*)d_in[5];
    const float* b2 = (const float*)d_in[6];
    const float* W3 = (const float*)d_in[7];
    const float* b3 = (const float*)d_in[8];
    const float* G  = (const float*)d_in[9];
    const float* mu = (const float*)d_in[10];
    const float* vt = (const float*)d_in[11];
    hipLaunchKernelGGL(sde_kernel, dim3(BATCH / MROWS), dim3(256), 0, stream,
                       x0, ts, dWs, W1, b1, W2, b2, W3, b3, G, mu, vt, (float*)d_out);
}